// Round 4
// baseline (167.516 us; speedup 1.0000x reference)
//
#include <hip/hip_runtime.h>

static constexpr int kH = 8;      // heads
static constexpr int kD = 32;     // head dim
static constexpr int kNN = 50000; // n_nodes (problem constant)

typedef float f4 __attribute__((ext_vector_type(4)));

__device__ __forceinline__ float dot8(const f4 a, const f4 b, const f4 c, const f4 d) {
  return a.x * b.x + a.y * b.y + a.z * b.z + a.w * b.w
       + c.x * d.x + c.y * d.y + c.z * d.z + c.w * d.w;
}

// Fused pass: v = exp(relu(q·a_q + k·a_k)); out = v; node_sum += v.
// One wave per edge, unrolled x2: per iteration the wave reads edges e and e+1
// (2KB of q, 2KB of k, all contiguous, 4 independent dwordx4 loads in flight).
// lane -> (h = lane>>3, sub = lane&7). Softmax shift-invariance + relu'd scores
// bounded (~<=10) => exp never overflows fp32; no seg_max pass needed.
__global__ void __launch_bounds__(256) score_exp_kernel(
    const float* __restrict__ q, const float* __restrict__ k,
    const float* __restrict__ attn, const int* __restrict__ index,
    float* __restrict__ out, float* __restrict__ node_sum, int nedges) {
  const int lane = threadIdx.x & 63;
  const int h = lane >> 3;
  const int sub = lane & 7;

  // per-lane attn fragment — loop-invariant
  const f4 aq = *reinterpret_cast<const f4*>(attn + h * (2 * kD) + sub * 4);
  const f4 ak = *reinterpret_cast<const f4*>(attn + h * (2 * kD) + kD + sub * 4);

  const int wave   = (blockIdx.x * blockDim.x + threadIdx.x) >> 6;
  const int nwaves = (gridDim.x * blockDim.x) >> 6;

  const f4* qv = reinterpret_cast<const f4*>(q);  // edge e -> f4 range [e*64, e*64+64)
  const f4* kv = reinterpret_cast<const f4*>(k);

  const int stride = nwaves * 2;
  for (int e0 = wave * 2; e0 < nedges; e0 += stride) {
    const int e1 = e0 + 1;
    const bool has1 = (e1 < nedges);

    // issue all 4 (or 2) loads up front — maximize loads in flight
    const f4 qA = __builtin_nontemporal_load(qv + (size_t)e0 * 64 + lane);
    const f4 kA = __builtin_nontemporal_load(kv + (size_t)e0 * 64 + lane);
    f4 qB, kB;
    if (has1) {
      qB = __builtin_nontemporal_load(qv + (size_t)e1 * 64 + lane);
      kB = __builtin_nontemporal_load(kv + (size_t)e1 * 64 + lane);
    }
    int nA = index[e0];
    int nB = has1 ? index[e1] : 0;

    float pA = dot8(qA, aq, kA, ak);
    pA += __shfl_xor(pA, 1);
    pA += __shfl_xor(pA, 2);
    pA += __shfl_xor(pA, 4);
    if (sub == 0) {
      float v = __expf(fmaxf(pA, 0.0f));
      out[(size_t)e0 * kH + h] = v;
      atomicAdd(node_sum + (size_t)nA * kH + h, v);
    }

    if (has1) {
      float pB = dot8(qB, aq, kB, ak);
      pB += __shfl_xor(pB, 1);
      pB += __shfl_xor(pB, 2);
      pB += __shfl_xor(pB, 4);
      if (sub == 0) {
        float v = __expf(fmaxf(pB, 0.0f));
        out[(size_t)e1 * kH + h] = v;
        atomicAdd(node_sum + (size_t)nB * kH + h, v);
      }
    }
  }
}

// Normalize: one thread per edge, all 8 heads vectorized (2x float4).
__global__ void __launch_bounds__(256) norm_kernel(
    const int* __restrict__ index, const float* __restrict__ node_sum,
    float* __restrict__ out, int nedges) {
  int e = blockIdx.x * blockDim.x + threadIdx.x;
  if (e >= nedges) return;
  int node = index[e];
  const f4 s0 = *reinterpret_cast<const f4*>(node_sum + (size_t)node * kH);
  const f4 s1 = *reinterpret_cast<const f4*>(node_sum + (size_t)node * kH + 4);
  f4* o = reinterpret_cast<f4*>(out + (size_t)e * kH);
  f4 v0 = o[0], v1 = o[1];
  v0.x /= s0.x; v0.y /= s0.y; v0.z /= s0.z; v0.w /= s0.w;
  v1.x /= s1.x; v1.y /= s1.y; v1.z /= s1.z; v1.w /= s1.w;
  o[0] = v0; o[1] = v1;
}

extern "C" void kernel_launch(void* const* d_in, const int* in_sizes, int n_in,
                              void* d_out, int out_size, void* d_ws, size_t ws_size,
                              hipStream_t stream) {
  const float* q    = (const float*)d_in[0];
  const float* k    = (const float*)d_in[1];
  const float* attn = (const float*)d_in[2];
  const int* index  = (const int*)d_in[3];

  const int E = in_sizes[3];  // 400000 edges

  float* out      = (float*)d_out;
  float* node_sum = (float*)d_ws;

  (void)hipMemsetAsync(node_sum, 0, (size_t)kNN * kH * sizeof(float), stream);

  // 2048 blocks x 256 = 8192 waves; each wave grid-strides over ~24 edge-pairs.
  score_exp_kernel<<<2048, 256, 0, stream>>>(q, k, attn, index, out, node_sum, E);

  norm_kernel<<<(E + 255) / 256, 256, 0, stream>>>(index, node_sum, out, E);
}

// Round 5
// 165.525 us; speedup vs baseline: 1.0120x; 1.0120x over previous
//
#include <hip/hip_runtime.h>

static constexpr int kH = 8;      // heads
static constexpr int kD = 32;     // head dim
static constexpr int kNN = 50000; // n_nodes (problem constant)

typedef float f4 __attribute__((ext_vector_type(4)));

__device__ __forceinline__ float dot8(const f4 a, const f4 b, const f4 c, const f4 d) {
  return a.x * b.x + a.y * b.y + a.z * b.z + a.w * b.w
       + c.x * d.x + c.y * d.y + c.z * d.z + c.w * d.w;
}

// Fused pass: v = exp(relu(q·a_q + k·a_k)); out = v; node_sum += v.
// One wave per 2 edges, BRANCHLESS x2 unroll (even-edge tail handled before
// the loop). Per iteration the wave reads 2KB of q + 2KB of k, 4 independent
// dwordx4 loads in flight, no exec-mask branches around the B-side.
// Softmax shift-invariance + relu'd bounded scores => no seg_max pass needed.
__global__ void __launch_bounds__(256) score_exp_kernel(
    const float* __restrict__ q, const float* __restrict__ k,
    const float* __restrict__ attn, const int* __restrict__ index,
    float* __restrict__ out, float* __restrict__ node_sum, int nedges) {
  const int lane = threadIdx.x & 63;
  const int h = lane >> 3;
  const int sub = lane & 7;

  // per-lane attn fragment — loop-invariant
  const f4 aq = *reinterpret_cast<const f4*>(attn + h * (2 * kD) + sub * 4);
  const f4 ak = *reinterpret_cast<const f4*>(attn + h * (2 * kD) + kD + sub * 4);

  const int wave   = (blockIdx.x * blockDim.x + threadIdx.x) >> 6;
  const int nwaves = (gridDim.x * blockDim.x) >> 6;

  const f4* qv = reinterpret_cast<const f4*>(q);  // edge e -> f4 range [e*64, e*64+64)
  const f4* kv = reinterpret_cast<const f4*>(k);

  // odd tail: wave 0 handles the last edge so the main loop is exactly even
  int neven = nedges & ~1;
  if ((nedges & 1) && wave == 0) {
    const int e = nedges - 1;
    const f4 q4 = __builtin_nontemporal_load(qv + (size_t)e * 64 + lane);
    const f4 k4 = __builtin_nontemporal_load(kv + (size_t)e * 64 + lane);
    float p = dot8(q4, aq, k4, ak);
    p += __shfl_xor(p, 1);
    p += __shfl_xor(p, 2);
    p += __shfl_xor(p, 4);
    if (sub == 0) {
      float v = __expf(fmaxf(p, 0.0f));
      out[(size_t)e * kH + h] = v;
      atomicAdd(node_sum + (size_t)index[e] * kH + h, v);
    }
  }

  const int stride = nwaves * 2;
  for (int e0 = wave * 2; e0 < neven; e0 += stride) {
    // all 4 loads issued unconditionally — cluster in flight
    const f4 qA = __builtin_nontemporal_load(qv + (size_t)e0 * 64 + lane);
    const f4 kA = __builtin_nontemporal_load(kv + (size_t)e0 * 64 + lane);
    const f4 qB = __builtin_nontemporal_load(qv + (size_t)e0 * 64 + 64 + lane);
    const f4 kB = __builtin_nontemporal_load(kv + (size_t)e0 * 64 + 64 + lane);
    const int2 nn = *reinterpret_cast<const int2*>(index + e0);  // e0 even

    float pA = dot8(qA, aq, kA, ak);
    float pB = dot8(qB, aq, kB, ak);
    pA += __shfl_xor(pA, 1);
    pB += __shfl_xor(pB, 1);
    pA += __shfl_xor(pA, 2);
    pB += __shfl_xor(pB, 2);
    pA += __shfl_xor(pA, 4);
    pB += __shfl_xor(pB, 4);

    if (sub == 0) {
      float vA = __expf(fmaxf(pA, 0.0f));
      float vB = __expf(fmaxf(pB, 0.0f));
      out[(size_t)e0 * kH + h] = vA;
      out[(size_t)e0 * kH + kH + h] = vB;
      atomicAdd(node_sum + (size_t)nn.x * kH + h, vA);
      atomicAdd(node_sum + (size_t)nn.y * kH + h, vB);
    }
  }
}

// Normalize: one thread per edge, all 8 heads vectorized (2x float4).
__global__ void __launch_bounds__(256) norm_kernel(
    const int* __restrict__ index, const float* __restrict__ node_sum,
    float* __restrict__ out, int nedges) {
  int e = blockIdx.x * blockDim.x + threadIdx.x;
  if (e >= nedges) return;
  int node = index[e];
  const f4 s0 = *reinterpret_cast<const f4*>(node_sum + (size_t)node * kH);
  const f4 s1 = *reinterpret_cast<const f4*>(node_sum + (size_t)node * kH + 4);
  f4* o = reinterpret_cast<f4*>(out + (size_t)e * kH);
  f4 v0 = o[0], v1 = o[1];
  v0.x /= s0.x; v0.y /= s0.y; v0.z /= s0.z; v0.w /= s0.w;
  v1.x /= s1.x; v1.y /= s1.y; v1.z /= s1.z; v1.w /= s1.w;
  o[0] = v0; o[1] = v1;
}

extern "C" void kernel_launch(void* const* d_in, const int* in_sizes, int n_in,
                              void* d_out, int out_size, void* d_ws, size_t ws_size,
                              hipStream_t stream) {
  const float* q    = (const float*)d_in[0];
  const float* k    = (const float*)d_in[1];
  const float* attn = (const float*)d_in[2];
  const int* index  = (const int*)d_in[3];

  const int E = in_sizes[3];  // 400000 edges

  float* out      = (float*)d_out;
  float* node_sum = (float*)d_ws;

  (void)hipMemsetAsync(node_sum, 0, (size_t)kNN * kH * sizeof(float), stream);

  // 2048 blocks x 256 = 8192 waves; each wave grid-strides over ~24 edge-pairs.
  score_exp_kernel<<<2048, 256, 0, stream>>>(q, k, attn, index, out, node_sum, E);

  norm_kernel<<<(E + 255) / 256, 256, 0, stream>>>(index, node_sum, out, E);
}

// Round 6
// 161.775 us; speedup vs baseline: 1.0355x; 1.0232x over previous
//
#include <hip/hip_runtime.h>

static constexpr int kH = 8;      // heads
static constexpr int kD = 32;     // head dim
static constexpr int kNN = 50000; // n_nodes (problem constant)
static constexpr int kRun = 8;    // edges per wave-run (atomic pre-aggregation window)

typedef float f4 __attribute__((ext_vector_type(4)));

__device__ __forceinline__ float dot8(const f4 a, const f4 b, const f4 c, const f4 d) {
  return a.x * b.x + a.y * b.y + a.z * b.z + a.w * b.w
       + c.x * d.x + c.y * d.y + c.z * d.z + c.w * d.w;
}

// Fused pass: v = exp(relu(q·a_q + k·a_k)); out = v; node_sum += v.
// One wave per edge within a run of kRun contiguous edges (tiled grid-stride:
// concurrent waves still cover one contiguous super-region for HBM locality).
// Inner loop is FORCED non-unrolled — R4/R5 proved extra in-flight loads
// regress; we are BW-bound, not latency-bound.
// The sorted index means consecutive edges share nodes: pre-aggregate the
// node sum in registers and flush one atomic per node-run (~4x fewer atomics,
// no cross-wave same-address contention).
__global__ void __launch_bounds__(256) score_exp_kernel(
    const float* __restrict__ q, const float* __restrict__ k,
    const float* __restrict__ attn, const int* __restrict__ index,
    float* __restrict__ out, float* __restrict__ node_sum, int nedges) {
  const int lane = threadIdx.x & 63;
  const int h = lane >> 3;
  const int sub = lane & 7;

  // per-lane attn fragment — loop-invariant
  const f4 aq = *reinterpret_cast<const f4*>(attn + h * (2 * kD) + sub * 4);
  const f4 ak = *reinterpret_cast<const f4*>(attn + h * (2 * kD) + kD + sub * 4);

  const int wave   = (blockIdx.x * blockDim.x + threadIdx.x) >> 6;
  const int nwaves = (gridDim.x * blockDim.x) >> 6;

  const f4* qv = reinterpret_cast<const f4*>(q);  // edge e -> f4 range [e*64, e*64+64)
  const f4* kv = reinterpret_cast<const f4*>(k);

  for (int base = wave * kRun; base < nedges; base += nwaves * kRun) {
    const int e_end = min(base + kRun, nedges);
    int cur = index[base];
    float acc = 0.0f;
    #pragma unroll 1
    for (int e = base; e < e_end; ++e) {
      const f4 q4 = __builtin_nontemporal_load(qv + (size_t)e * 64 + lane);
      const f4 k4 = __builtin_nontemporal_load(kv + (size_t)e * 64 + lane);
      const int node = index[e];

      float p = dot8(q4, aq, k4, ak);
      p += __shfl_xor(p, 1);
      p += __shfl_xor(p, 2);
      p += __shfl_xor(p, 4);
      const float v = __expf(fmaxf(p, 0.0f));  // uniform within each 8-lane group

      if (sub == 0) out[(size_t)e * kH + h] = v;

      if (node != cur) {  // wave-uniform branch (node boundary)
        if (sub == 0) atomicAdd(node_sum + (size_t)cur * kH + h, acc);
        acc = 0.0f;
        cur = node;
      }
      acc += v;
    }
    if (sub == 0) atomicAdd(node_sum + (size_t)cur * kH + h, acc);
  }
}

// Normalize: one thread per edge, all 8 heads vectorized (2x float4).
__global__ void __launch_bounds__(256) norm_kernel(
    const int* __restrict__ index, const float* __restrict__ node_sum,
    float* __restrict__ out, int nedges) {
  int e = blockIdx.x * blockDim.x + threadIdx.x;
  if (e >= nedges) return;
  int node = index[e];
  const f4 s0 = *reinterpret_cast<const f4*>(node_sum + (size_t)node * kH);
  const f4 s1 = *reinterpret_cast<const f4*>(node_sum + (size_t)node * kH + 4);
  f4* o = reinterpret_cast<f4*>(out + (size_t)e * kH);
  f4 v0 = o[0], v1 = o[1];
  v0.x /= s0.x; v0.y /= s0.y; v0.z /= s0.z; v0.w /= s0.w;
  v1.x /= s1.x; v1.y /= s1.y; v1.z /= s1.z; v1.w /= s1.w;
  o[0] = v0; o[1] = v1;
}

extern "C" void kernel_launch(void* const* d_in, const int* in_sizes, int n_in,
                              void* d_out, int out_size, void* d_ws, size_t ws_size,
                              hipStream_t stream) {
  const float* q    = (const float*)d_in[0];
  const float* k    = (const float*)d_in[1];
  const float* attn = (const float*)d_in[2];
  const int* index  = (const int*)d_in[3];

  const int E = in_sizes[3];  // 400000 edges

  float* out      = (float*)d_out;
  float* node_sum = (float*)d_ws;

  (void)hipMemsetAsync(node_sum, 0, (size_t)kNN * kH * sizeof(float), stream);

  // 2048 blocks x 256 = 8192 waves; each wave covers runs of 8 contiguous edges.
  score_exp_kernel<<<2048, 256, 0, stream>>>(q, k, attn, index, out, node_sum, E);

  norm_kernel<<<(E + 255) / 256, 256, 0, stream>>>(index, node_sum, out, E);
}

// Round 7
// 155.846 us; speedup vs baseline: 1.0749x; 1.0380x over previous
//
#include <hip/hip_runtime.h>

static constexpr int kH = 8;      // heads
static constexpr int kD = 32;     // head dim
static constexpr int kNN = 50000; // n_nodes (problem constant)

typedef float f4 __attribute__((ext_vector_type(4)));

__device__ __forceinline__ float dot8(const f4 a, const f4 b, const f4 c, const f4 d) {
  return a.x * b.x + a.y * b.y + a.z * b.z + a.w * b.w
       + c.x * d.x + c.y * d.y + c.z * d.z + c.w * d.w;
}

// Fused pass: v = exp(relu(q·a_q + k·a_k)); out = v; node_sum += v.
// R3 structure (empirical best: one edge per wave-iteration, no unroll) with:
//  - __launch_bounds__(256, 8): pin the 8-blocks/CU (32 waves/CU) occupancy
//    tier by capping VGPR allocation at 64 — R4/R5/R6 all regressed and all
//    added registers; this guards the occupancy cliff.
//  - pointer-increment addressing: no per-iteration 64-bit multiply.
// Softmax shift-invariance + relu'd bounded scores => no seg_max pass needed.
__global__ void __launch_bounds__(256, 8) score_exp_kernel(
    const float* __restrict__ q, const float* __restrict__ k,
    const float* __restrict__ attn, const int* __restrict__ index,
    float* __restrict__ out, float* __restrict__ node_sum, int nedges) {
  const int lane = threadIdx.x & 63;
  const int h = lane >> 3;
  const int sub = lane & 7;

  // per-lane attn fragment — loop-invariant
  const f4 aq = *reinterpret_cast<const f4*>(attn + h * (2 * kD) + sub * 4);
  const f4 ak = *reinterpret_cast<const f4*>(attn + h * (2 * kD) + kD + sub * 4);

  const int wave   = (blockIdx.x * blockDim.x + threadIdx.x) >> 6;
  const int nwaves = (gridDim.x * blockDim.x) >> 6;

  const f4* qp = reinterpret_cast<const f4*>(q) + (size_t)wave * 64 + lane;
  const f4* kp = reinterpret_cast<const f4*>(k) + (size_t)wave * 64 + lane;
  const size_t pstep = (size_t)nwaves * 64;

  #pragma unroll 1
  for (int e = wave; e < nedges; e += nwaves, qp += pstep, kp += pstep) {
    const f4 q4 = __builtin_nontemporal_load(qp);
    const f4 k4 = __builtin_nontemporal_load(kp);

    float p = dot8(q4, aq, k4, ak);
    p += __shfl_xor(p, 1);
    p += __shfl_xor(p, 2);
    p += __shfl_xor(p, 4);

    if (sub == 0) {
      float v = __expf(fmaxf(p, 0.0f));
      out[(size_t)e * kH + h] = v;
      atomicAdd(node_sum + (size_t)index[e] * kH + h, v);
    }
  }
}

// Normalize: one thread per edge, all 8 heads vectorized (2x float4).
__global__ void __launch_bounds__(256, 8) norm_kernel(
    const int* __restrict__ index, const float* __restrict__ node_sum,
    float* __restrict__ out, int nedges) {
  int e = blockIdx.x * blockDim.x + threadIdx.x;
  if (e >= nedges) return;
  int node = index[e];
  const f4 s0 = *reinterpret_cast<const f4*>(node_sum + (size_t)node * kH);
  const f4 s1 = *reinterpret_cast<const f4*>(node_sum + (size_t)node * kH + 4);
  f4* o = reinterpret_cast<f4*>(out + (size_t)e * kH);
  f4 v0 = o[0], v1 = o[1];
  v0.x /= s0.x; v0.y /= s0.y; v0.z /= s0.z; v0.w /= s0.w;
  v1.x /= s1.x; v1.y /= s1.y; v1.z /= s1.z; v1.w /= s1.w;
  o[0] = v0; o[1] = v1;
}

extern "C" void kernel_launch(void* const* d_in, const int* in_sizes, int n_in,
                              void* d_out, int out_size, void* d_ws, size_t ws_size,
                              hipStream_t stream) {
  const float* q    = (const float*)d_in[0];
  const float* k    = (const float*)d_in[1];
  const float* attn = (const float*)d_in[2];
  const int* index  = (const int*)d_in[3];

  const int E = in_sizes[3];  // 400000 edges

  float* out      = (float*)d_out;
  float* node_sum = (float*)d_ws;

  (void)hipMemsetAsync(node_sum, 0, (size_t)kNN * kH * sizeof(float), stream);

  // 2048 blocks x 256 = 8192 waves; each wave grid-strides over ~49 edges.
  score_exp_kernel<<<2048, 256, 0, stream>>>(q, k, attn, index, out, node_sum, E);

  norm_kernel<<<(E + 255) / 256, 256, 0, stream>>>(index, node_sum, out, E);
}